// Round 7
// baseline (386.454 us; speedup 1.0000x reference)
//
#include <hip/hip_runtime.h>

// Problem constants (match reference)
constexpr int B = 16, N = 16, H = 512, W = 512;
constexpr int HW = H * W;              // 262144
constexpr int S = 2;                   // blocks per (b,n) plane
constexpr int CHUNK = HW / S;          // 131072 elements (512 KB)
constexpr int THREADS = 512;           // 8 waves/block
constexpr int NBLK = B * N * S;        // 512 blocks = 2 per CU (self-balancing)
constexpr int BN = B * N;              // 256

// Native clang vector type — __builtin_nontemporal_load needs this.
typedef float floatx4 __attribute__((ext_vector_type(4)));

// ws layout (floats): [0..255] ov, [256..511] inter, [512..767] ts,
//                     [768..1023] arrival counters (as int). 4 KB memset.
__global__ __launch_bounds__(THREADS) void fused_kernel(
    const float* __restrict__ masks,   // (B,N,H,W)
    const float* __restrict__ target,  // (B,H,W)
    const int*   __restrict__ boxes,   // (B,N,4) xyxy
    float* __restrict__ ws,
    float* __restrict__ out)           // (B,N,2)
{
    // XCD-aware remap (HW round-robins block i -> XCD i&7): each XCD owns
    // 2 b's, so target[b] (2 MB) stays resident in that XCD's 4 MiB L2.
    const int i0   = blockIdx.x;
    const int xcd  = i0 & 7;
    const int slot = i0 >> 3;               // 0..63
    const int b    = xcd * 2 + (slot >> 5);
    const int n    = (slot >> 1) & 15;
    const int s    = slot & 1;
    const int bn   = b * N + n;

    const int x1 = boxes[bn * 4 + 0];
    const int y1 = boxes[bn * 4 + 1];
    const int x2 = boxes[bn * 4 + 2];
    const int y2 = boxes[bn * 4 + 3];

    const floatx4* m4 = (const floatx4*)(masks + (size_t)bn * HW + (size_t)s * CHUNK);
    const floatx4* t4 = (const floatx4*)(target + (size_t)b * HW + (size_t)s * CHUNK);
    const int base_h = (s * CHUNK) >> 9;    // chunk starts on a row boundary

    float ov = 0.f, inter = 0.f, ts = 0.f;
    // CHUNK/4 = 32768 float4s; 64 iters/thread, 16 B/lane coalesced.
    // masks streamed once -> non-temporal (keep target L2-resident).
    #pragma unroll 8
    for (int i = threadIdx.x; i < CHUNK / 4; i += THREADS) {
        floatx4 m = __builtin_nontemporal_load(&m4[i]);
        floatx4 t = t4[i];
        ov += m.x * t.x + m.y * t.y + m.z * t.z + m.w * t.w;
        ts += t.x + t.y + t.z + t.w;
        int h = base_h + (i >> 7);  // 128 float4 per row (W=512)
        int w = (i & 127) << 2;     // 4-aligned; row never crossed in a float4
        if (h >= y1 && h < y2) {
            if (w     >= x1 && w     < x2) inter += t.x;
            if (w + 1 >= x1 && w + 1 < x2) inter += t.y;
            if (w + 2 >= x1 && w + 2 < x2) inter += t.z;
            if (w + 3 >= x1 && w + 3 < x2) inter += t.w;
        }
    }

    // wave(64) shuffle reduction, then cross-wave via LDS
    for (int off = 32; off > 0; off >>= 1) {
        ov    += __shfl_down(ov, off);
        inter += __shfl_down(inter, off);
        ts    += __shfl_down(ts, off);
    }
    __shared__ float red[3][THREADS / 64];
    const int wave = threadIdx.x >> 6;
    if ((threadIdx.x & 63) == 0) {
        red[0][wave] = ov;
        red[1][wave] = inter;
        red[2][wave] = ts;
    }
    __syncthreads();

    if (threadIdx.x == 0) {
        float o = 0.f, it = 0.f, t = 0.f;
        #pragma unroll
        for (int k = 0; k < THREADS / 64; ++k) {
            o += red[0][k]; it += red[1][k]; t += red[2][k];
        }
        // Device-scope accumulation (S=2 adds per sum -> exact & deterministic)
        atomicAdd(&ws[0 * BN + bn], o);
        atomicAdd(&ws[1 * BN + bn], it);
        atomicAdd(&ws[2 * BN + bn], t);
        __threadfence();
        int* ctr = (int*)(ws + 3 * BN);
        int old = atomicAdd(&ctr[bn], 1);
        if (old == S - 1) {
            // Last arrival for this bn: read totals via coherent RMW
            // (immune to cross-XCD L2 staleness), finalize, write out.
            float O  = atomicAdd(&ws[0 * BN + bn], 0.f);
            float IT = atomicAdd(&ws[1 * BN + bn], 0.f);
            float T  = atomicAdd(&ws[2 * BN + bn], 0.f);
            int bw = min(x2, W) - max(x1, 0); if (bw < 0) bw = 0;
            int bh = min(y2, H) - max(y1, 0); if (bh < 0) bh = 0;
            float box_area = (float)bw * (float)bh;
            float uni = box_area + T - IT;
            out[bn * 2 + 0] = O;
            out[bn * 2 + 1] = IT / (uni + 1e-8f);
        }
    }
}

extern "C" void kernel_launch(void* const* d_in, const int* in_sizes, int n_in,
                              void* d_out, int out_size, void* d_ws, size_t ws_size,
                              hipStream_t stream) {
    const float* masks  = (const float*)d_in[0];   // (B,N,H,W) fp32
    const float* target = (const float*)d_in[1];   // (B,H,W)   fp32
    const int*   boxes  = (const int*)d_in[2];     // (B,N,4)   int32
    float* out = (float*)d_out;
    float* ws  = (float*)d_ws;

    // Zero the 3*256 accumulators + 256 counters (4 KB — capture-legal).
    hipMemsetAsync(ws, 0, 4 * BN * sizeof(float), stream);
    fused_kernel<<<NBLK, THREADS, 0, stream>>>(masks, target, boxes, ws, out);
}

// Round 8
// 357.233 us; speedup vs baseline: 1.0818x; 1.0818x over previous
//
#include <hip/hip_runtime.h>

// Problem constants (match reference)
constexpr int B = 16, N = 16, H = 512, W = 512;
constexpr int HW = H * W;            // 262144
constexpr int THREADS = 1024;        // 16 waves/block, grid = 256 = 1 block/CU
constexpr int NWAVE = THREADS / 64;

// Native clang vector type — __builtin_nontemporal_load needs this (HIP's
// float4 is a class and is rejected).
typedef float floatx4 __attribute__((ext_vector_type(4)));

// One block per (b,n): streams masks[b,n] (1 MB, non-temporal) and target[b]
// (1 MB, L2-resident via XCD-aware remap), computes overlap, box∩target and
// target_area in one pass, finalizes IoU in-block. No workspace, no atomics.
// Measured best structure (R5: 358.0 µs total; split/coop/atomic variants all
// regressed — R3 377, R6 fail, R7 386).
__global__ __launch_bounds__(THREADS) void fused_kernel(
    const float* __restrict__ masks,   // (B,N,H,W)
    const float* __restrict__ target,  // (B,H,W)
    const int*   __restrict__ boxes,   // (B,N,4) xyxy
    float* __restrict__ out)           // (B,N,2)
{
    // XCD-aware remap: HW dispatch round-robins block i -> XCD (i & 7).
    // Map so all 16 n-blocks of a given b land on ONE XCD (2 b's per XCD,
    // 32 blocks = that XCD's 32 CUs): target[b] (1 MB) stays resident in the
    // XCD's 4 MiB L2 instead of being replicated into all 8 L2s.
    const int i0   = blockIdx.x;
    const int xcd  = i0 & 7;
    const int slot = i0 >> 3;              // 0..31
    const int b    = xcd * 2 + (slot >> 4);
    const int n    = slot & 15;
    const int bn   = b * N + n;

    const int x1 = boxes[bn * 4 + 0];
    const int y1 = boxes[bn * 4 + 1];
    const int x2 = boxes[bn * 4 + 2];
    const int y2 = boxes[bn * 4 + 3];

    const floatx4* m4 = (const floatx4*)(masks + (size_t)bn * HW);
    const floatx4* t4 = (const floatx4*)(target + (size_t)b * HW);

    float ov = 0.f, inter = 0.f, ts = 0.f;
    // HW/4 = 65536 float4s; 64 iters/thread, 16 B/lane coalesced.
    // masks: streamed exactly once -> non-temporal (don't evict target in L2).
    #pragma unroll 8
    for (int i = threadIdx.x; i < HW / 4; i += THREADS) {
        floatx4 m = __builtin_nontemporal_load(&m4[i]);
        floatx4 t = t4[i];
        ov += m.x * t.x + m.y * t.y + m.z * t.z + m.w * t.w;
        ts += t.x + t.y + t.z + t.w;
        int h = i >> 7;            // (i*4) / W, W = 512
        int w = (i & 127) << 2;    // (i*4) % W, 4-aligned, row never crossed
        if (h >= y1 && h < y2) {
            if (w     >= x1 && w     < x2) inter += t.x;
            if (w + 1 >= x1 && w + 1 < x2) inter += t.y;
            if (w + 2 >= x1 && w + 2 < x2) inter += t.z;
            if (w + 3 >= x1 && w + 3 < x2) inter += t.w;
        }
    }

    // wave(64) shuffle reduction, then cross-wave via LDS
    for (int off = 32; off > 0; off >>= 1) {
        ov    += __shfl_down(ov, off);
        inter += __shfl_down(inter, off);
        ts    += __shfl_down(ts, off);
    }
    __shared__ float red[3][NWAVE];
    const int wave = threadIdx.x >> 6;
    if ((threadIdx.x & 63) == 0) {
        red[0][wave] = ov;
        red[1][wave] = inter;
        red[2][wave] = ts;
    }
    __syncthreads();
    if (threadIdx.x == 0) {
        float o = 0.f, it = 0.f, t = 0.f;
        #pragma unroll
        for (int k = 0; k < NWAVE; ++k) { o += red[0][k]; it += red[1][k]; t += red[2][k]; }
        int bw = min(x2, W) - max(x1, 0); if (bw < 0) bw = 0;
        int bh = min(y2, H) - max(y1, 0); if (bh < 0) bh = 0;
        float box_area = (float)bw * (float)bh;
        float uni = box_area + t - it;
        out[bn * 2 + 0] = o;
        out[bn * 2 + 1] = it / (uni + 1e-8f);
    }
}

extern "C" void kernel_launch(void* const* d_in, const int* in_sizes, int n_in,
                              void* d_out, int out_size, void* d_ws, size_t ws_size,
                              hipStream_t stream) {
    const float* masks  = (const float*)d_in[0];   // (B,N,H,W) fp32
    const float* target = (const float*)d_in[1];   // (B,H,W)   fp32
    const int*   boxes  = (const int*)d_in[2];     // (B,N,4)   int32
    float* out = (float*)d_out;

    fused_kernel<<<B * N, THREADS, 0, stream>>>(masks, target, boxes, out);
}